// Round 10
// baseline (53.240 us; speedup 1.0000x reference)
//
#include <hip/hip_runtime.h>
#include <hip/hip_bf16.h>
#include <float.h>

// ChamferLoss: preds [B,N,3] f32, gts [B,N,3] f32 -> scalar f32
// R10: drop the standalone reduce dispatch. mfma blocks store partials and
// signal completion through a TWO-LEVEL counter (64 subs x 16 + 1 master --
// avoids R8's same-address atomic serialization tail); the last block
// reduces all partials in fixed order (deterministic) and writes out.
// Counters zeroed by chamfer_prep (no extra dispatch). Visibility via
// __hip_atomic release/acquire at AGENT scope (cross-XCD safe).

#define BLK  256

typedef _Float16 f16x8 __attribute__((ext_vector_type(8)));
typedef float    f32x16 __attribute__((ext_vector_type(16)));
typedef float    f32x2 __attribute__((ext_vector_type(2)));
typedef float    f32x4 __attribute__((ext_vector_type(4)));

__device__ __forceinline__ unsigned int enc_f32(float f) {
    unsigned int u = __float_as_uint(f);
    return (u & 0x80000000u) ? ~u : (u | 0x80000000u);
}
__device__ __forceinline__ float dec_f32(unsigned int k) {
    return __uint_as_float((k & 0x80000000u) ? (k & 0x7FFFFFFFu) : ~k);
}

// ---------------- MFMA path ----------------

// Pack per-target fragment: 8 f16 = {tx,ty,tz,tn_hi,tn_lo,0,0,0}
// Also zeroes the 65 completion counters (block 0).
__global__ __launch_bounds__(BLK) void chamfer_prep(
    const float* __restrict__ preds, const float* __restrict__ gts,
    uint4* __restrict__ frag, unsigned int* __restrict__ counters, int N) {
    if (blockIdx.x == 0 && threadIdx.x < 65) counters[threadIdx.x] = 0u;
    int gid = blockIdx.x * BLK + threadIdx.x;     // [0, 2*4*N)
    int dir = gid / (4 * N);
    int rem = gid - dir * 4 * N;
    int b = rem / N, i = rem - b * N;
    const float* src = (dir == 0) ? gts : preds;  // dir0: queries=preds
    const float* p = src + ((size_t)b * N + i) * 3;
    float x = p[0], y = p[1], z = p[2];
    _Float16 hx = (_Float16)x, hy = (_Float16)y, hz = (_Float16)z;
    float xr = (float)hx, yr = (float)hy, zr = (float)hz;
    float tn = xr * xr + yr * yr + zr * zr;
    _Float16 hi = (_Float16)tn;
    _Float16 lo = (_Float16)(tn - (float)hi);
    f16x8 f;
    f[0] = hx; f[1] = hy; f[2] = hz; f[3] = hi; f[4] = lo;
    f[5] = (_Float16)0.f; f[6] = (_Float16)0.f; f[7] = (_Float16)0.f;
    frag[gid] = __builtin_bit_cast(uint4, f);
}

#define MFMA16(A, B, C) __builtin_amdgcn_mfma_f32_32x32x16_f16((A), (B), (C), 0, 0, 0)

// Block: 64 queries (2 strips of 32), 4 waves split targets (N/4 each).
// Body: 1 tile (32 targets) x 2 strips = 2 MFMA + 16 min3.
__global__ __launch_bounds__(BLK, 4) void chamfer_mfma(
    const float* __restrict__ preds, const float* __restrict__ gts,
    const uint4* __restrict__ frag, float* __restrict__ partials,
    unsigned int* __restrict__ counters, float* __restrict__ out,
    int N, int out_size) {

    const int dir  = blockIdx.z;
    const int b    = blockIdx.y;
    const int tid  = threadIdx.x;
    const int wave = tid >> 6;
    const int lane = tid & 63;
    const int col  = lane & 31;
    const int qb   = blockIdx.x * 64;

    const float* Q = ((dir == 0) ? preds : gts) + (size_t)b * N * 3;
    const uint4* F = frag + ((size_t)dir * 4 + b) * N;

    // B fragments (queries) for the 2 strips; lanes>=32 (k=8..15) -> 0
    f16x8 bf0, bf1;
    {
        const _Float16 c0 = (_Float16)0.f, c1 = (_Float16)1.f, cm2 = (_Float16)(-2.f);
        int q0 = qb + col, q1 = qb + 32 + col;
        float x0 = Q[q0*3], y0 = Q[q0*3+1], z0 = Q[q0*3+2];
        float x1 = Q[q1*3], y1 = Q[q1*3+1], z1 = Q[q1*3+2];
        bf0[0] = (_Float16)x0 * cm2; bf0[1] = (_Float16)y0 * cm2; bf0[2] = (_Float16)z0 * cm2;
        bf0[3] = c1; bf0[4] = c1; bf0[5] = c0; bf0[6] = c0; bf0[7] = c0;
        bf1[0] = (_Float16)x1 * cm2; bf1[1] = (_Float16)y1 * cm2; bf1[2] = (_Float16)z1 * cm2;
        bf1[3] = c1; bf1[4] = c1; bf1[5] = c0; bf1[6] = c0; bf1[7] = c0;
        if (lane >= 32) {
            #pragma unroll
            for (int j = 0; j < 8; ++j) { bf0[j] = c0; bf1[j] = c0; }
        }
    }

    f32x16 cz;
    float rm0[8], rm1[8];
    #pragma unroll
    for (int j = 0; j < 16; ++j) cz[j] = 0.f;
    #pragma unroll
    for (int j = 0; j < 8; ++j) { rm0[j] = FLT_MAX; rm1[j] = FLT_MAX; }

    // Wave owns N/4 targets; 4 bodies (128 targets) per iteration.
    // Lanes>=32 feed k=8..15 (B zero there) -> alias to tile frag 0.
    const int NIT = N >> 9;                        // (N/4)/128
    const uint4* p = F + (size_t)wave * (N >> 2) + ((lane < 32) ? col : 0);

    uint4 f0 = p[0], f1 = p[32], f2 = p[64], f3 = p[96];

#define BODY(FR, OFF)                                                   \
    {                                                                   \
        f16x8 a = __builtin_bit_cast(f16x8, FR);                        \
        f32x16 x0 = MFMA16(a, bf0, cz);                                 \
        f32x16 x1 = MFMA16(a, bf1, cz);                                 \
        _Pragma("unroll")                                               \
        for (int j = 0; j < 8; ++j) {                                   \
            rm0[j] = fminf(fminf(x0[2*j], x0[2*j+1]), rm0[j]);          \
            rm1[j] = fminf(fminf(x1[2*j], x1[2*j+1]), rm1[j]);          \
        }                                                               \
        FR = p[OFF];                                                    \
    }

    for (int it = 0; it < NIT; ++it) {
        BODY(f0, 128)
        BODY(f1, 160)
        BODY(f2, 192)
        BODY(f3, 224)
        p += 128;
    }
#undef BODY

    float m0 = rm0[0], m1 = rm1[0];
    #pragma unroll
    for (int j = 1; j < 8; ++j) { m0 = fminf(m0, rm0[j]); m1 = fminf(m1, rm1[j]); }

    __shared__ float lds[4][2][64];
    __shared__ int amLastSh;
    lds[wave][0][lane] = m0;
    lds[wave][1][lane] = m1;
    __syncthreads();

    const int nb = gridDim.x * 8;                  // total blocks (x * 4 * 2)
    if (tid < 64) {
        int s = tid >> 5, c = tid & 31;
        float m = FLT_MAX;
        #pragma unroll
        for (int w = 0; w < 4; ++w)
            m = fminf(m, fminf(lds[w][s][c], lds[w][s][c + 32]));
        int q = qb + s * 32 + c;
        float x = Q[q*3], y = Q[q*3+1], z = Q[q*3+2];
        float xr = (float)(_Float16)x, yr = (float)(_Float16)y, zr = (float)(_Float16)z;
        float val = m + (xr * xr + yr * yr + zr * zr);
        #pragma unroll
        for (int off = 32; off > 0; off >>= 1)
            val += __shfl_down(val, off, 64);
        if (tid == 0) {
            int flat = blockIdx.x + gridDim.x * (blockIdx.y + 4 * blockIdx.z);
            __hip_atomic_store(&partials[flat], val, __ATOMIC_RELEASE,
                               __HIP_MEMORY_SCOPE_AGENT);
            // two-level completion counter: 64 subs x (nb/64), then master
            unsigned so = __hip_atomic_fetch_add(&counters[flat & 63], 1u,
                              __ATOMIC_ACQ_REL, __HIP_MEMORY_SCOPE_AGENT);
            int last = 0;
            if (so == (unsigned)(nb >> 6) - 1u) {
                unsigned mo = __hip_atomic_fetch_add(&counters[64], 1u,
                                  __ATOMIC_ACQ_REL, __HIP_MEMORY_SCOPE_AGENT);
                last = (mo == 63u);
            }
            amLastSh = last;
        }
    }
    __syncthreads();

    if (amLastSh) {
        float s = 0.f;
        for (int i = tid; i < nb; i += BLK)
            s += __hip_atomic_load(&partials[i], __ATOMIC_ACQUIRE,
                                   __HIP_MEMORY_SCOPE_AGENT);
        __shared__ float psum[BLK / 64];
        #pragma unroll
        for (int off = 32; off > 0; off >>= 1) s += __shfl_down(s, off, 64);
        if ((tid & 63) == 0) psum[tid >> 6] = s;
        __syncthreads();
        if (tid == 0) {
            float t = 0.f;
            #pragma unroll
            for (int w = 0; w < BLK / 64; ++w) t += psum[w];
            out[0] = t;
        }
        for (int i = 1 + tid; i < out_size; i += BLK) out[i] = 0.f;
    }
}

// ---------------- Fallback path (R5 VALU version) ----------------

#define SEG  32
#define Q    8

__device__ __forceinline__ float min3f(float a, float b, float c) {
    float r;
    asm("v_min3_f32 %0, %1, %2, %3" : "=v"(r) : "v"(a), "v"(b), "v"(c));
    return r;
}
__device__ __forceinline__ f32x2 pk_fma(f32x2 a, f32x2 b, f32x2 c) {
    f32x2 d;
    asm("v_pk_fma_f32 %0, %1, %2, %3" : "=v"(d) : "v"(a), "v"(b), "v"(c));
    return d;
}
__device__ __forceinline__ f32x2 pk_mul(f32x2 a, f32x2 b) {
    f32x2 d;
    asm("v_pk_mul_f32 %0, %1, %2" : "=v"(d) : "v"(a), "v"(b));
    return d;
}

__global__ __launch_bounds__(BLK, 4) void chamfer_min_kernel(
    const float* __restrict__ preds, const float* __restrict__ gts,
    unsigned int* __restrict__ keys, int N) {
    const int seg = blockIdx.z % SEG;
    const int dir = blockIdx.z / SEG;
    const int b   = blockIdx.y;
    const int tid = threadIdx.x;
    const int TT  = N / SEG;
    const float* Aq = dir == 0 ? preds : gts;
    const float* Bt = dir == 0 ? gts   : preds;
    const float* Ab = Aq + (size_t)b * N * 3;
    const float* Bb = Bt + (size_t)b * N * 3;
    __shared__ f32x2 shx[256], shy[256], shz[256];
    const int qbase = blockIdx.x * (BLK * Q);
    f32x2 a2x[Q], a2y[Q], a2z[Q];
    float an[Q]; bool vq[Q];
    #pragma unroll
    for (int q = 0; q < Q; ++q) {
        int idx = qbase + q * BLK + tid;
        vq[q] = idx < N;
        int ci = vq[q] ? idx : 0;
        float ax = Ab[ci*3], ay = Ab[ci*3+1], az = Ab[ci*3+2];
        a2x[q] = f32x2{-2.f*ax, -2.f*ax};
        a2y[q] = f32x2{-2.f*ay, -2.f*ay};
        a2z[q] = f32x2{-2.f*az, -2.f*az};
        an[q]  = ax*ax + ay*ay + az*az;
    }
    for (int p = tid; p < (TT >> 1); p += BLK) {
        int j0 = seg * TT + 2 * p;
        const f32x2* src = (const f32x2*)(Bb + (size_t)j0 * 3);
        f32x2 v01 = src[0], v23 = src[1], v45 = src[2];
        shx[p] = f32x2{v01.x, v23.y};
        shy[p] = f32x2{v01.y, v45.x};
        shz[p] = f32x2{v23.x, v45.y};
    }
    __syncthreads();
    float m[Q];
    #pragma unroll
    for (int q = 0; q < Q; ++q) m[q] = FLT_MAX;
    const f32x4* X4 = (const f32x4*)shx;
    const f32x4* Y4 = (const f32x4*)shy;
    const f32x4* Z4 = (const f32x4*)shz;
    const int KITER = TT >> 2;
    #pragma unroll 2
    for (int k = 0; k < KITER; ++k) {
        f32x4 X = X4[k], Y = Y4[k], Z = Z4[k];
        f32x2 w01 = pk_fma(Z.lo, Z.lo, pk_fma(Y.lo, Y.lo, pk_mul(X.lo, X.lo)));
        f32x2 w23 = pk_fma(Z.hi, Z.hi, pk_fma(Y.hi, Y.hi, pk_mul(X.hi, X.hi)));
        #pragma unroll
        for (int q = 0; q < Q; ++q) {
            f32x2 d0 = pk_fma(a2x[q], X.lo, pk_fma(a2y[q], Y.lo, pk_fma(a2z[q], Z.lo, w01)));
            f32x2 d1 = pk_fma(a2x[q], X.hi, pk_fma(a2y[q], Y.hi, pk_fma(a2z[q], Z.hi, w23)));
            m[q] = min3f(d0.x, d0.y, m[q]);
            m[q] = min3f(d1.x, d1.y, m[q]);
        }
    }
    #pragma unroll
    for (int q = 0; q < Q; ++q) {
        if (vq[q]) {
            int idx = qbase + q * BLK + tid;
            atomicMin(keys + ((size_t)(dir*4 + b) * N + idx), enc_f32(m[q] + an[q]));
        }
    }
}

__global__ __launch_bounds__(BLK) void chamfer_sum_kernel(
    const unsigned int* __restrict__ keys, float* __restrict__ out, int M) {
    __shared__ float psum[BLK / 64];
    int gid = blockIdx.x * BLK + threadIdx.x;
    int stride = gridDim.x * BLK;
    float s = 0.f;
    for (int i = gid; i < M; i += stride) s += dec_f32(keys[i]);
    for (int off = 32; off > 0; off >>= 1) s += __shfl_down(s, off, 64);
    if ((threadIdx.x & 63) == 0) psum[threadIdx.x >> 6] = s;
    __syncthreads();
    if (threadIdx.x == 0) {
        float t = 0.f;
        for (int w = 0; w < BLK / 64; ++w) t += psum[w];
        atomicAdd(out, t);
    }
}

extern "C" void kernel_launch(void* const* d_in, const int* in_sizes, int n_in,
                              void* d_out, int out_size, void* d_ws, size_t ws_size,
                              hipStream_t stream) {
    const float* preds = (const float*)d_in[0];
    const float* gts   = (const float*)d_in[1];
    float* out = (float*)d_out;

    const int B = 4, D = 3;
    const int N = in_sizes[0] / (B * D);   // 8192

    // ws layout: [frag: 2*B*N uint4][4KB pad][partials: nb floats][counters: 65 u32]
    const size_t frag_bytes = (size_t)2 * B * N * sizeof(uint4);
    const int    nb         = (N / 64) * B * 2;
    const size_t part_off   = frag_bytes + 4096;
    const size_t cnt_off    = part_off + (size_t)nb * sizeof(float);
    const size_t need       = cnt_off + 65 * sizeof(unsigned int);

    // nb must be a multiple of 64 for the two-level counter (N%512==0 ensures it)
    if (ws_size >= need && (N % 512) == 0) {
        uint4* frag = (uint4*)d_ws;
        float* partials = (float*)((char*)d_ws + part_off);
        unsigned int* counters = (unsigned int*)((char*)d_ws + cnt_off);
        int npts = 2 * B * N;
        chamfer_prep<<<npts / BLK, BLK, 0, stream>>>(preds, gts, frag, counters, N);
        dim3 grid(N / 64, B, 2);
        chamfer_mfma<<<grid, BLK, 0, stream>>>(preds, gts, frag, partials,
                                               counters, out, N, out_size);
    } else {
        hipMemsetAsync(out, 0, sizeof(float) * out_size, stream);
        const size_t keys_bytes = (size_t)2 * B * N * sizeof(unsigned int);
        unsigned int* keys = (unsigned int*)d_ws;
        hipMemsetAsync(keys, 0xFF, keys_bytes, stream);
        dim3 grid((N + BLK * Q - 1) / (BLK * Q), B, 2 * SEG);
        chamfer_min_kernel<<<grid, BLK, 0, stream>>>(preds, gts, keys, N);
        chamfer_sum_kernel<<<64, BLK, 0, stream>>>(keys, out, 2 * B * N);
    }
}

// Round 11
// 27.955 us; speedup vs baseline: 1.9045x; 1.9045x over previous
//
#include <hip/hip_runtime.h>
#include <hip/hip_bf16.h>
#include <float.h>

// ChamferLoss: preds [B,N,3] f32, gts [B,N,3] f32 -> scalar f32
// R11: revert R10's inline reduce (codegen regression: epilogue graft spilled
// the loop, VGPR 48->32, latency-bound). R9 3-dispatch structure restored.
// New: 8B fragments {x,y,z,||t||^2} all-f16 (K=4 embedding; error budget ~1
// vs threshold 30.5) -> halves L2 traffic; depth-8 prefetch (same reg budget
// as R9's depth-4x16B) -> 352cyc lookahead > L2 latency.

#define BLK  256

typedef _Float16 f16x8 __attribute__((ext_vector_type(8)));
typedef _Float16 f16x4 __attribute__((ext_vector_type(4)));
typedef float    f32x16 __attribute__((ext_vector_type(16)));
typedef float    f32x2 __attribute__((ext_vector_type(2)));
typedef float    f32x4 __attribute__((ext_vector_type(4)));

__device__ __forceinline__ unsigned int enc_f32(float f) {
    unsigned int u = __float_as_uint(f);
    return (u & 0x80000000u) ? ~u : (u | 0x80000000u);
}
__device__ __forceinline__ float dec_f32(unsigned int k) {
    return __uint_as_float((k & 0x80000000u) ? (k & 0x7FFFFFFFu) : ~k);
}

// ---------------- MFMA path ----------------

// Pack per-target fragment: 4 f16 = {tx,ty,tz,||t||^2} (8 bytes)
__global__ __launch_bounds__(BLK) void chamfer_prep(
    const float* __restrict__ preds, const float* __restrict__ gts,
    uint2* __restrict__ frag, int N) {
    int gid = blockIdx.x * BLK + threadIdx.x;     // [0, 2*4*N)
    int dir = gid / (4 * N);
    int rem = gid - dir * 4 * N;
    int b = rem / N, i = rem - b * N;
    const float* src = (dir == 0) ? gts : preds;  // dir0: queries=preds
    const float* p = src + ((size_t)b * N + i) * 3;
    float x = p[0], y = p[1], z = p[2];
    _Float16 hx = (_Float16)x, hy = (_Float16)y, hz = (_Float16)z;
    float xr = (float)hx, yr = (float)hy, zr = (float)hz;
    float tn = xr * xr + yr * yr + zr * zr;
    f16x4 f;
    f[0] = hx; f[1] = hy; f[2] = hz; f[3] = (_Float16)tn;
    frag[gid] = __builtin_bit_cast(uint2, f);
}

#define MFMA16(A, B, C) __builtin_amdgcn_mfma_f32_32x32x16_f16((A), (B), (C), 0, 0, 0)

// Block: 64 queries (2 strips of 32), 4 waves split targets (N/4 each).
// Body: 1 tile (32 targets) x 2 strips = 2 MFMA + 16 min3.
// Epilogue: plain store of the block partial (R9-proven, no atomics).
__global__ __launch_bounds__(BLK, 4) void chamfer_mfma(
    const float* __restrict__ preds, const float* __restrict__ gts,
    const uint2* __restrict__ frag, float* __restrict__ partials, int N) {

    const int dir  = blockIdx.z;
    const int b    = blockIdx.y;
    const int tid  = threadIdx.x;
    const int wave = tid >> 6;
    const int lane = tid & 63;
    const int col  = lane & 31;
    const int qb   = blockIdx.x * 64;

    const float* Q = ((dir == 0) ? preds : gts) + (size_t)b * N * 3;
    const uint2* F = frag + ((size_t)dir * 4 + b) * N;

    // B fragments (queries): k0-2 = -2q, k3 = 1, k4-7 = 0; lanes>=32 -> 0
    f16x8 bf0, bf1;
    {
        const _Float16 c0 = (_Float16)0.f, c1 = (_Float16)1.f, cm2 = (_Float16)(-2.f);
        int q0 = qb + col, q1 = qb + 32 + col;
        float x0 = Q[q0*3], y0 = Q[q0*3+1], z0 = Q[q0*3+2];
        float x1 = Q[q1*3], y1 = Q[q1*3+1], z1 = Q[q1*3+2];
        bf0[0] = (_Float16)x0 * cm2; bf0[1] = (_Float16)y0 * cm2; bf0[2] = (_Float16)z0 * cm2;
        bf0[3] = c1; bf0[4] = c0; bf0[5] = c0; bf0[6] = c0; bf0[7] = c0;
        bf1[0] = (_Float16)x1 * cm2; bf1[1] = (_Float16)y1 * cm2; bf1[2] = (_Float16)z1 * cm2;
        bf1[3] = c1; bf1[4] = c0; bf1[5] = c0; bf1[6] = c0; bf1[7] = c0;
        if (lane >= 32) {
            #pragma unroll
            for (int j = 0; j < 8; ++j) { bf0[j] = c0; bf1[j] = c0; }
        }
    }

    f32x16 cz;
    float rm0[8], rm1[8];
    #pragma unroll
    for (int j = 0; j < 16; ++j) cz[j] = 0.f;
    #pragma unroll
    for (int j = 0; j < 8; ++j) { rm0[j] = FLT_MAX; rm1[j] = FLT_MAX; }

    // Wave owns N/4 targets; 8 bodies (256 targets) per iteration, depth-8
    // prefetch. Lanes>=32 feed k=8..15 (B zero) -> alias to tile frag 0.
    const int NIT = N >> 10;                       // (N/4)/256
    const uint2* p = F + (size_t)wave * (N >> 2) + ((lane < 32) ? col : 0);

    uint2 f0 = p[0],   f1 = p[32],  f2 = p[64],  f3 = p[96];
    uint2 f4 = p[128], f5 = p[160], f6 = p[192], f7 = p[224];

#define BODY(FR, OFF)                                                   \
    {                                                                   \
        f16x4 alo = __builtin_bit_cast(f16x4, FR);                      \
        f16x8 a;                                                        \
        a[0] = alo[0]; a[1] = alo[1]; a[2] = alo[2]; a[3] = alo[3];     \
        a[4] = (_Float16)0.f; a[5] = (_Float16)0.f;                     \
        a[6] = (_Float16)0.f; a[7] = (_Float16)0.f;                     \
        f32x16 x0 = MFMA16(a, bf0, cz);                                 \
        f32x16 x1 = MFMA16(a, bf1, cz);                                 \
        _Pragma("unroll")                                               \
        for (int j = 0; j < 8; ++j) {                                   \
            rm0[j] = fminf(fminf(x0[2*j], x0[2*j+1]), rm0[j]);          \
            rm1[j] = fminf(fminf(x1[2*j], x1[2*j+1]), rm1[j]);          \
        }                                                               \
        FR = p[OFF];                                                    \
    }

    for (int it = 0; it < NIT; ++it) {
        BODY(f0, 256)
        BODY(f1, 288)
        BODY(f2, 320)
        BODY(f3, 352)
        BODY(f4, 384)
        BODY(f5, 416)
        BODY(f6, 448)
        BODY(f7, 480)
        p += 256;
    }
#undef BODY

    float m0 = rm0[0], m1 = rm1[0];
    #pragma unroll
    for (int j = 1; j < 8; ++j) { m0 = fminf(m0, rm0[j]); m1 = fminf(m1, rm1[j]); }

    __shared__ float lds[4][2][64];
    lds[wave][0][lane] = m0;
    lds[wave][1][lane] = m1;
    __syncthreads();

    if (tid < 64) {
        int s = tid >> 5, c = tid & 31;
        float m = FLT_MAX;
        #pragma unroll
        for (int w = 0; w < 4; ++w)
            m = fminf(m, fminf(lds[w][s][c], lds[w][s][c + 32]));
        int q = qb + s * 32 + c;
        float x = Q[q*3], y = Q[q*3+1], z = Q[q*3+2];
        float xr = (float)(_Float16)x, yr = (float)(_Float16)y, zr = (float)(_Float16)z;
        float val = m + (xr * xr + yr * yr + zr * zr);
        #pragma unroll
        for (int off = 32; off > 0; off >>= 1)
            val += __shfl_down(val, off, 64);
        if (tid == 0) {
            int flat = blockIdx.x + gridDim.x * (blockIdx.y + 4 * blockIdx.z);
            partials[flat] = val;
        }
    }
}

// 1-block deterministic reduce: fixed per-thread slot sets, fixed tree.
__global__ __launch_bounds__(BLK) void chamfer_reduce(
    const float* __restrict__ partials, float* __restrict__ out,
    int nparts, int out_size) {
    const int tid = threadIdx.x;
    float s = 0.f;
    for (int i = tid; i < nparts; i += BLK) s += partials[i];
    __shared__ float psum[BLK / 64];
    #pragma unroll
    for (int off = 32; off > 0; off >>= 1) s += __shfl_down(s, off, 64);
    if ((tid & 63) == 0) psum[tid >> 6] = s;
    __syncthreads();
    if (tid == 0) {
        float t = 0.f;
        #pragma unroll
        for (int w = 0; w < BLK / 64; ++w) t += psum[w];
        out[0] = t;
    }
    for (int i = 1 + tid; i < out_size; i += BLK) out[i] = 0.f;
}

// ---------------- Fallback path (R5 VALU version) ----------------

#define SEG  32
#define Q    8

__device__ __forceinline__ float min3f(float a, float b, float c) {
    float r;
    asm("v_min3_f32 %0, %1, %2, %3" : "=v"(r) : "v"(a), "v"(b), "v"(c));
    return r;
}
__device__ __forceinline__ f32x2 pk_fma(f32x2 a, f32x2 b, f32x2 c) {
    f32x2 d;
    asm("v_pk_fma_f32 %0, %1, %2, %3" : "=v"(d) : "v"(a), "v"(b), "v"(c));
    return d;
}
__device__ __forceinline__ f32x2 pk_mul(f32x2 a, f32x2 b) {
    f32x2 d;
    asm("v_pk_mul_f32 %0, %1, %2" : "=v"(d) : "v"(a), "v"(b));
    return d;
}

__global__ __launch_bounds__(BLK, 4) void chamfer_min_kernel(
    const float* __restrict__ preds, const float* __restrict__ gts,
    unsigned int* __restrict__ keys, int N) {
    const int seg = blockIdx.z % SEG;
    const int dir = blockIdx.z / SEG;
    const int b   = blockIdx.y;
    const int tid = threadIdx.x;
    const int TT  = N / SEG;
    const float* Aq = dir == 0 ? preds : gts;
    const float* Bt = dir == 0 ? gts   : preds;
    const float* Ab = Aq + (size_t)b * N * 3;
    const float* Bb = Bt + (size_t)b * N * 3;
    __shared__ f32x2 shx[256], shy[256], shz[256];
    const int qbase = blockIdx.x * (BLK * Q);
    f32x2 a2x[Q], a2y[Q], a2z[Q];
    float an[Q]; bool vq[Q];
    #pragma unroll
    for (int q = 0; q < Q; ++q) {
        int idx = qbase + q * BLK + tid;
        vq[q] = idx < N;
        int ci = vq[q] ? idx : 0;
        float ax = Ab[ci*3], ay = Ab[ci*3+1], az = Ab[ci*3+2];
        a2x[q] = f32x2{-2.f*ax, -2.f*ax};
        a2y[q] = f32x2{-2.f*ay, -2.f*ay};
        a2z[q] = f32x2{-2.f*az, -2.f*az};
        an[q]  = ax*ax + ay*ay + az*az;
    }
    for (int p = tid; p < (TT >> 1); p += BLK) {
        int j0 = seg * TT + 2 * p;
        const f32x2* src = (const f32x2*)(Bb + (size_t)j0 * 3);
        f32x2 v01 = src[0], v23 = src[1], v45 = src[2];
        shx[p] = f32x2{v01.x, v23.y};
        shy[p] = f32x2{v01.y, v45.x};
        shz[p] = f32x2{v23.x, v45.y};
    }
    __syncthreads();
    float m[Q];
    #pragma unroll
    for (int q = 0; q < Q; ++q) m[q] = FLT_MAX;
    const f32x4* X4 = (const f32x4*)shx;
    const f32x4* Y4 = (const f32x4*)shy;
    const f32x4* Z4 = (const f32x4*)shz;
    const int KITER = TT >> 2;
    #pragma unroll 2
    for (int k = 0; k < KITER; ++k) {
        f32x4 X = X4[k], Y = Y4[k], Z = Z4[k];
        f32x2 w01 = pk_fma(Z.lo, Z.lo, pk_fma(Y.lo, Y.lo, pk_mul(X.lo, X.lo)));
        f32x2 w23 = pk_fma(Z.hi, Z.hi, pk_fma(Y.hi, Y.hi, pk_mul(X.hi, X.hi)));
        #pragma unroll
        for (int q = 0; q < Q; ++q) {
            f32x2 d0 = pk_fma(a2x[q], X.lo, pk_fma(a2y[q], Y.lo, pk_fma(a2z[q], Z.lo, w01)));
            f32x2 d1 = pk_fma(a2x[q], X.hi, pk_fma(a2y[q], Y.hi, pk_fma(a2z[q], Z.hi, w23)));
            m[q] = min3f(d0.x, d0.y, m[q]);
            m[q] = min3f(d1.x, d1.y, m[q]);
        }
    }
    #pragma unroll
    for (int q = 0; q < Q; ++q) {
        if (vq[q]) {
            int idx = qbase + q * BLK + tid;
            atomicMin(keys + ((size_t)(dir*4 + b) * N + idx), enc_f32(m[q] + an[q]));
        }
    }
}

__global__ __launch_bounds__(BLK) void chamfer_sum_kernel(
    const unsigned int* __restrict__ keys, float* __restrict__ out, int M) {
    __shared__ float psum[BLK / 64];
    int gid = blockIdx.x * BLK + threadIdx.x;
    int stride = gridDim.x * BLK;
    float s = 0.f;
    for (int i = gid; i < M; i += stride) s += dec_f32(keys[i]);
    for (int off = 32; off > 0; off >>= 1) s += __shfl_down(s, off, 64);
    if ((threadIdx.x & 63) == 0) psum[threadIdx.x >> 6] = s;
    __syncthreads();
    if (threadIdx.x == 0) {
        float t = 0.f;
        for (int w = 0; w < BLK / 64; ++w) t += psum[w];
        atomicAdd(out, t);
    }
}

extern "C" void kernel_launch(void* const* d_in, const int* in_sizes, int n_in,
                              void* d_out, int out_size, void* d_ws, size_t ws_size,
                              hipStream_t stream) {
    const float* preds = (const float*)d_in[0];
    const float* gts   = (const float*)d_in[1];
    float* out = (float*)d_out;

    const int B = 4, D = 3;
    const int N = in_sizes[0] / (B * D);   // 8192

    // ws layout: [frag: 2*B*N uint2][4KB pad][partials: nb floats]
    const size_t frag_bytes = (size_t)2 * B * N * sizeof(uint2);
    const int    nb         = (N / 64) * B * 2;
    const size_t part_off   = frag_bytes + 4096;
    const size_t need       = part_off + (size_t)nb * sizeof(float);

    if (ws_size >= need && (N % 1024) == 0) {
        uint2* frag = (uint2*)d_ws;
        float* partials = (float*)((char*)d_ws + part_off);
        int npts = 2 * B * N;
        chamfer_prep<<<npts / BLK, BLK, 0, stream>>>(preds, gts, frag, N);
        dim3 grid(N / 64, B, 2);
        chamfer_mfma<<<grid, BLK, 0, stream>>>(preds, gts, frag, partials, N);
        chamfer_reduce<<<1, BLK, 0, stream>>>(partials, out, nb, out_size);
    } else {
        hipMemsetAsync(out, 0, sizeof(float) * out_size, stream);
        const size_t keys_bytes = (size_t)2 * B * N * sizeof(unsigned int);
        unsigned int* keys = (unsigned int*)d_ws;
        hipMemsetAsync(keys, 0xFF, keys_bytes, stream);
        dim3 grid((N + BLK * Q - 1) / (BLK * Q), B, 2 * SEG);
        chamfer_min_kernel<<<grid, BLK, 0, stream>>>(preds, gts, keys, N);
        chamfer_sum_kernel<<<64, BLK, 0, stream>>>(keys, out, 2 * B * N);
    }
}

// Round 13
// 27.853 us; speedup vs baseline: 1.9114x; 1.0036x over previous
//
#include <hip/hip_runtime.h>
#include <hip/hip_bf16.h>
#include <float.h>

// ChamferLoss: preds [B,N,3] f32, gts [B,N,3] f32 -> scalar f32
// R13: R11 restored verbatim (R12's inline-asm min3 on MFMA outputs = inf;
// MFMA-result consumption must stay compiler-generated). Single change:
// chamfer_mfma __launch_bounds__(256,4) -> (256,2). The 128-VGPR cap was
// plausibly forcing MFMA result tuples into AGPRs (hidden v_accvgpr_read per
// fminf operand); 256-reg budget lets everything live in arch VGPRs.
// Depth-8 prefetch covers latency at the lower occupancy.

#define BLK  256

typedef _Float16 f16x8 __attribute__((ext_vector_type(8)));
typedef _Float16 f16x4 __attribute__((ext_vector_type(4)));
typedef float    f32x16 __attribute__((ext_vector_type(16)));
typedef float    f32x2 __attribute__((ext_vector_type(2)));
typedef float    f32x4 __attribute__((ext_vector_type(4)));

__device__ __forceinline__ unsigned int enc_f32(float f) {
    unsigned int u = __float_as_uint(f);
    return (u & 0x80000000u) ? ~u : (u | 0x80000000u);
}
__device__ __forceinline__ float dec_f32(unsigned int k) {
    return __uint_as_float((k & 0x80000000u) ? (k & 0x7FFFFFFFu) : ~k);
}

// ---------------- MFMA path ----------------

// Pack per-target fragment: 4 f16 = {tx,ty,tz,||t||^2} (8 bytes)
__global__ __launch_bounds__(BLK) void chamfer_prep(
    const float* __restrict__ preds, const float* __restrict__ gts,
    uint2* __restrict__ frag, int N) {
    int gid = blockIdx.x * BLK + threadIdx.x;     // [0, 2*4*N)
    int dir = gid / (4 * N);
    int rem = gid - dir * 4 * N;
    int b = rem / N, i = rem - b * N;
    const float* src = (dir == 0) ? gts : preds;  // dir0: queries=preds
    const float* p = src + ((size_t)b * N + i) * 3;
    float x = p[0], y = p[1], z = p[2];
    _Float16 hx = (_Float16)x, hy = (_Float16)y, hz = (_Float16)z;
    float xr = (float)hx, yr = (float)hy, zr = (float)hz;
    float tn = xr * xr + yr * yr + zr * zr;
    f16x4 f;
    f[0] = hx; f[1] = hy; f[2] = hz; f[3] = (_Float16)tn;
    frag[gid] = __builtin_bit_cast(uint2, f);
}

#define MFMA16(A, B, C) __builtin_amdgcn_mfma_f32_32x32x16_f16((A), (B), (C), 0, 0, 0)

// Block: 64 queries (2 strips of 32), 4 waves split targets (N/4 each).
// Body: 1 tile (32 targets) x 2 strips = 2 MFMA + 16 min3 (fminf-fused).
// Epilogue: plain store of the block partial (R9-proven, no atomics).
__global__ __launch_bounds__(BLK, 2) void chamfer_mfma(
    const float* __restrict__ preds, const float* __restrict__ gts,
    const uint2* __restrict__ frag, float* __restrict__ partials, int N) {

    const int dir  = blockIdx.z;
    const int b    = blockIdx.y;
    const int tid  = threadIdx.x;
    const int wave = tid >> 6;
    const int lane = tid & 63;
    const int col  = lane & 31;
    const int qb   = blockIdx.x * 64;

    const float* Q = ((dir == 0) ? preds : gts) + (size_t)b * N * 3;
    const uint2* F = frag + ((size_t)dir * 4 + b) * N;

    // B fragments (queries): k0-2 = -2q, k3 = 1, k4-7 = 0; lanes>=32 -> 0
    f16x8 bf0, bf1;
    {
        const _Float16 c0 = (_Float16)0.f, c1 = (_Float16)1.f, cm2 = (_Float16)(-2.f);
        int q0 = qb + col, q1 = qb + 32 + col;
        float x0 = Q[q0*3], y0 = Q[q0*3+1], z0 = Q[q0*3+2];
        float x1 = Q[q1*3], y1 = Q[q1*3+1], z1 = Q[q1*3+2];
        bf0[0] = (_Float16)x0 * cm2; bf0[1] = (_Float16)y0 * cm2; bf0[2] = (_Float16)z0 * cm2;
        bf0[3] = c1; bf0[4] = c0; bf0[5] = c0; bf0[6] = c0; bf0[7] = c0;
        bf1[0] = (_Float16)x1 * cm2; bf1[1] = (_Float16)y1 * cm2; bf1[2] = (_Float16)z1 * cm2;
        bf1[3] = c1; bf1[4] = c0; bf1[5] = c0; bf1[6] = c0; bf1[7] = c0;
        if (lane >= 32) {
            #pragma unroll
            for (int j = 0; j < 8; ++j) { bf0[j] = c0; bf1[j] = c0; }
        }
    }

    f32x16 cz;
    float rm0[8], rm1[8];
    #pragma unroll
    for (int j = 0; j < 16; ++j) cz[j] = 0.f;
    #pragma unroll
    for (int j = 0; j < 8; ++j) { rm0[j] = FLT_MAX; rm1[j] = FLT_MAX; }

    // Wave owns N/4 targets; 8 bodies (256 targets) per iteration, depth-8
    // prefetch. Lanes>=32 feed k=8..15 (B zero) -> alias to tile frag 0.
    const int NIT = N >> 10;                       // (N/4)/256
    const uint2* p = F + (size_t)wave * (N >> 2) + ((lane < 32) ? col : 0);

    uint2 f0 = p[0],   f1 = p[32],  f2 = p[64],  f3 = p[96];
    uint2 f4 = p[128], f5 = p[160], f6 = p[192], f7 = p[224];

#define BODY(FR, OFF)                                                   \
    {                                                                   \
        f16x4 alo = __builtin_bit_cast(f16x4, FR);                      \
        f16x8 a;                                                        \
        a[0] = alo[0]; a[1] = alo[1]; a[2] = alo[2]; a[3] = alo[3];     \
        a[4] = (_Float16)0.f; a[5] = (_Float16)0.f;                     \
        a[6] = (_Float16)0.f; a[7] = (_Float16)0.f;                     \
        f32x16 x0 = MFMA16(a, bf0, cz);                                 \
        f32x16 x1 = MFMA16(a, bf1, cz);                                 \
        _Pragma("unroll")                                               \
        for (int j = 0; j < 8; ++j) {                                   \
            rm0[j] = fminf(fminf(x0[2*j], x0[2*j+1]), rm0[j]);          \
            rm1[j] = fminf(fminf(x1[2*j], x1[2*j+1]), rm1[j]);          \
        }                                                               \
        FR = p[OFF];                                                    \
    }

    for (int it = 0; it < NIT; ++it) {
        BODY(f0, 256)
        BODY(f1, 288)
        BODY(f2, 320)
        BODY(f3, 352)
        BODY(f4, 384)
        BODY(f5, 416)
        BODY(f6, 448)
        BODY(f7, 480)
        p += 256;
    }
#undef BODY

    float m0 = rm0[0], m1 = rm1[0];
    #pragma unroll
    for (int j = 1; j < 8; ++j) { m0 = fminf(m0, rm0[j]); m1 = fminf(m1, rm1[j]); }

    __shared__ float lds[4][2][64];
    lds[wave][0][lane] = m0;
    lds[wave][1][lane] = m1;
    __syncthreads();

    if (tid < 64) {
        int s = tid >> 5, c = tid & 31;
        float m = FLT_MAX;
        #pragma unroll
        for (int w = 0; w < 4; ++w)
            m = fminf(m, fminf(lds[w][s][c], lds[w][s][c + 32]));
        int q = qb + s * 32 + c;
        float x = Q[q*3], y = Q[q*3+1], z = Q[q*3+2];
        float xr = (float)(_Float16)x, yr = (float)(_Float16)y, zr = (float)(_Float16)z;
        float val = m + (xr * xr + yr * yr + zr * zr);
        #pragma unroll
        for (int off = 32; off > 0; off >>= 1)
            val += __shfl_down(val, off, 64);
        if (tid == 0) {
            int flat = blockIdx.x + gridDim.x * (blockIdx.y + 4 * blockIdx.z);
            partials[flat] = val;
        }
    }
}

// 1-block deterministic reduce: fixed per-thread slot sets, fixed tree.
__global__ __launch_bounds__(BLK) void chamfer_reduce(
    const float* __restrict__ partials, float* __restrict__ out,
    int nparts, int out_size) {
    const int tid = threadIdx.x;
    float s = 0.f;
    for (int i = tid; i < nparts; i += BLK) s += partials[i];
    __shared__ float psum[BLK / 64];
    #pragma unroll
    for (int off = 32; off > 0; off >>= 1) s += __shfl_down(s, off, 64);
    if ((tid & 63) == 0) psum[tid >> 6] = s;
    __syncthreads();
    if (tid == 0) {
        float t = 0.f;
        #pragma unroll
        for (int w = 0; w < BLK / 64; ++w) t += psum[w];
        out[0] = t;
    }
    for (int i = 1 + tid; i < out_size; i += BLK) out[i] = 0.f;
}

// ---------------- Fallback path (R5 VALU version) ----------------

#define SEG  32
#define Q    8

__device__ __forceinline__ float min3f(float a, float b, float c) {
    float r;
    asm("v_min3_f32 %0, %1, %2, %3" : "=v"(r) : "v"(a), "v"(b), "v"(c));
    return r;
}
__device__ __forceinline__ f32x2 pk_fma(f32x2 a, f32x2 b, f32x2 c) {
    f32x2 d;
    asm("v_pk_fma_f32 %0, %1, %2, %3" : "=v"(d) : "v"(a), "v"(b), "v"(c));
    return d;
}
__device__ __forceinline__ f32x2 pk_mul(f32x2 a, f32x2 b) {
    f32x2 d;
    asm("v_pk_mul_f32 %0, %1, %2" : "=v"(d) : "v"(a), "v"(b));
    return d;
}

__global__ __launch_bounds__(BLK, 4) void chamfer_min_kernel(
    const float* __restrict__ preds, const float* __restrict__ gts,
    unsigned int* __restrict__ keys, int N) {
    const int seg = blockIdx.z % SEG;
    const int dir = blockIdx.z / SEG;
    const int b   = blockIdx.y;
    const int tid = threadIdx.x;
    const int TT  = N / SEG;
    const float* Aq = dir == 0 ? preds : gts;
    const float* Bt = dir == 0 ? gts   : preds;
    const float* Ab = Aq + (size_t)b * N * 3;
    const float* Bb = Bt + (size_t)b * N * 3;
    __shared__ f32x2 shx[256], shy[256], shz[256];
    const int qbase = blockIdx.x * (BLK * Q);
    f32x2 a2x[Q], a2y[Q], a2z[Q];
    float an[Q]; bool vq[Q];
    #pragma unroll
    for (int q = 0; q < Q; ++q) {
        int idx = qbase + q * BLK + tid;
        vq[q] = idx < N;
        int ci = vq[q] ? idx : 0;
        float ax = Ab[ci*3], ay = Ab[ci*3+1], az = Ab[ci*3+2];
        a2x[q] = f32x2{-2.f*ax, -2.f*ax};
        a2y[q] = f32x2{-2.f*ay, -2.f*ay};
        a2z[q] = f32x2{-2.f*az, -2.f*az};
        an[q]  = ax*ax + ay*ay + az*az;
    }
    for (int p = tid; p < (TT >> 1); p += BLK) {
        int j0 = seg * TT + 2 * p;
        const f32x2* src = (const f32x2*)(Bb + (size_t)j0 * 3);
        f32x2 v01 = src[0], v23 = src[1], v45 = src[2];
        shx[p] = f32x2{v01.x, v23.y};
        shy[p] = f32x2{v01.y, v45.x};
        shz[p] = f32x2{v23.x, v45.y};
    }
    __syncthreads();
    float m[Q];
    #pragma unroll
    for (int q = 0; q < Q; ++q) m[q] = FLT_MAX;
    const f32x4* X4 = (const f32x4*)shx;
    const f32x4* Y4 = (const f32x4*)shy;
    const f32x4* Z4 = (const f32x4*)shz;
    const int KITER = TT >> 2;
    #pragma unroll 2
    for (int k = 0; k < KITER; ++k) {
        f32x4 X = X4[k], Y = Y4[k], Z = Z4[k];
        f32x2 w01 = pk_fma(Z.lo, Z.lo, pk_fma(Y.lo, Y.lo, pk_mul(X.lo, X.lo)));
        f32x2 w23 = pk_fma(Z.hi, Z.hi, pk_fma(Y.hi, Y.hi, pk_mul(X.hi, X.hi)));
        #pragma unroll
        for (int q = 0; q < Q; ++q) {
            f32x2 d0 = pk_fma(a2x[q], X.lo, pk_fma(a2y[q], Y.lo, pk_fma(a2z[q], Z.lo, w01)));
            f32x2 d1 = pk_fma(a2x[q], X.hi, pk_fma(a2y[q], Y.hi, pk_fma(a2z[q], Z.hi, w23)));
            m[q] = min3f(d0.x, d0.y, m[q]);
            m[q] = min3f(d1.x, d1.y, m[q]);
        }
    }
    #pragma unroll
    for (int q = 0; q < Q; ++q) {
        if (vq[q]) {
            int idx = qbase + q * BLK + tid;
            atomicMin(keys + ((size_t)(dir*4 + b) * N + idx), enc_f32(m[q] + an[q]));
        }
    }
}

__global__ __launch_bounds__(BLK) void chamfer_sum_kernel(
    const unsigned int* __restrict__ keys, float* __restrict__ out, int M) {
    __shared__ float psum[BLK / 64];
    int gid = blockIdx.x * BLK + threadIdx.x;
    int stride = gridDim.x * BLK;
    float s = 0.f;
    for (int i = gid; i < M; i += stride) s += dec_f32(keys[i]);
    for (int off = 32; off > 0; off >>= 1) s += __shfl_down(s, off, 64);
    if ((threadIdx.x & 63) == 0) psum[threadIdx.x >> 6] = s;
    __syncthreads();
    if (threadIdx.x == 0) {
        float t = 0.f;
        for (int w = 0; w < BLK / 64; ++w) t += psum[w];
        atomicAdd(out, t);
    }
}

extern "C" void kernel_launch(void* const* d_in, const int* in_sizes, int n_in,
                              void* d_out, int out_size, void* d_ws, size_t ws_size,
                              hipStream_t stream) {
    const float* preds = (const float*)d_in[0];
    const float* gts   = (const float*)d_in[1];
    float* out = (float*)d_out;

    const int B = 4, D = 3;
    const int N = in_sizes[0] / (B * D);   // 8192

    // ws layout: [frag: 2*B*N uint2][4KB pad][partials: nb floats]
    const size_t frag_bytes = (size_t)2 * B * N * sizeof(uint2);
    const int    nb         = (N / 64) * B * 2;
    const size_t part_off   = frag_bytes + 4096;
    const size_t need       = part_off + (size_t)nb * sizeof(float);

    if (ws_size >= need && (N % 1024) == 0) {
        uint2* frag = (uint2*)d_ws;
        float* partials = (float*)((char*)d_ws + part_off);
        int npts = 2 * B * N;
        chamfer_prep<<<npts / BLK, BLK, 0, stream>>>(preds, gts, frag, N);
        dim3 grid(N / 64, B, 2);
        chamfer_mfma<<<grid, BLK, 0, stream>>>(preds, gts, frag, partials, N);
        chamfer_reduce<<<1, BLK, 0, stream>>>(partials, out, nb, out_size);
    } else {
        hipMemsetAsync(out, 0, sizeof(float) * out_size, stream);
        const size_t keys_bytes = (size_t)2 * B * N * sizeof(unsigned int);
        unsigned int* keys = (unsigned int*)d_ws;
        hipMemsetAsync(keys, 0xFF, keys_bytes, stream);
        dim3 grid((N + BLK * Q - 1) / (BLK * Q), B, 2 * SEG);
        chamfer_min_kernel<<<grid, BLK, 0, stream>>>(preds, gts, keys, N);
        chamfer_sum_kernel<<<64, BLK, 0, stream>>>(keys, out, 2 * B * N);
    }
}